// Round 1
// baseline (6960.026 us; speedup 1.0000x reference)
//
#include <hip/hip_runtime.h>
#include <hip/hip_bf16.h>

// GCN 3-layer: per layer  h = A_in @ W ;  agg[col] += h[row]*norm ;  out = relu(agg + b)
// Fusions: bias pre-initialized into scatter destination; relu fused into next GEMM's
// A-tile load. All fp32 (no fp32 MFMA on CDNA4; bf16 precision risk vs 6.8e-3 threshold).

#define K_DIM 128
#define KC 32
#define TILE_M 64

__host__ __device__ static inline long long cdiv_ll(long long a, long long b) { return (a + b - 1) / b; }

// ---------------- degree / norm ----------------
__global__ __launch_bounds__(256) void deg_kernel(const int* __restrict__ col, float* __restrict__ deg, int E) {
    int e = blockIdx.x * 256 + threadIdx.x;
    if (e < E) atomicAdd(&deg[col[e]], 1.0f);
}

__global__ __launch_bounds__(256) void dinv_kernel(float* __restrict__ deg, int N) {
    int n = blockIdx.x * 256 + threadIdx.x;
    if (n < N) {
        float d = deg[n];
        deg[n] = (d > 0.0f) ? (1.0f / sqrtf(d)) : 0.0f;   // in-place: deg -> dinv
    }
}

__global__ __launch_bounds__(256) void norm_kernel(const int* __restrict__ row, const int* __restrict__ col,
                                                   const float* __restrict__ dinv, float* __restrict__ norm, int E) {
    int e = blockIdx.x * 256 + threadIdx.x;
    if (e < E) norm[e] = dinv[row[e]] * dinv[col[e]];
}

// ---------------- bias broadcast init ----------------
template <int C>
__global__ __launch_bounds__(256) void init_bias_kernel(float* __restrict__ buf, const float* __restrict__ b,
                                                        long long total) {
    long long i = (long long)blockIdx.x * 256 + threadIdx.x;
    if (i < total) buf[i] = b[(int)(i & (C - 1))];
}

// ---------------- fp32 tiled GEMM:  C[M x COUT] = act(A[M x 128]) @ W[128 x COUT] ----------------
template <int COUT, bool RELU>
__global__ __launch_bounds__(256) void gemm_kernel(const float* __restrict__ A, const float* __restrict__ W,
                                                   float* __restrict__ C, int M) {
    constexpr int TX = COUT / 4;        // threads covering cols (32 or 16), 4 cols each
    constexpr int TY = 256 / TX;        // row groups (8 or 16)
    constexpr int RPT = TILE_M / TY;    // rows per thread (8 or 4)
    constexpr int AS_STRIDE = TILE_M + 4;  // pad keeps float4 alignment, limits bank conflicts

    __shared__ float As[KC][AS_STRIDE]; // transposed: As[k][row]
    __shared__ float Ws[KC][COUT];

    const int t = threadIdx.x;
    const int tx = t % TX;
    const int ty = t / TX;
    const int row0 = blockIdx.x * TILE_M;

    float acc[RPT][4];
#pragma unroll
    for (int i = 0; i < RPT; ++i)
#pragma unroll
        for (int j = 0; j < 4; ++j) acc[i][j] = 0.0f;

    for (int kc = 0; kc < K_DIM; kc += KC) {
        // --- stage A tile (64 rows x 32 k), transposed, relu fused ---
        {
            int r = t / 8;               // 0..31
            int k4 = (t % 8) * 4;        // 0,4,...,28
#pragma unroll
            for (int pass = 0; pass < 2; ++pass) {
                int rr = r + pass * 32;
                int grow = row0 + rr;
                float4 v = make_float4(0.f, 0.f, 0.f, 0.f);
                if (grow < M) v = *(const float4*)&A[(size_t)grow * K_DIM + kc + k4];
                if (RELU) {
                    v.x = fmaxf(v.x, 0.f); v.y = fmaxf(v.y, 0.f);
                    v.z = fmaxf(v.z, 0.f); v.w = fmaxf(v.w, 0.f);
                }
                As[k4 + 0][rr] = v.x; As[k4 + 1][rr] = v.y;
                As[k4 + 2][rr] = v.z; As[k4 + 3][rr] = v.w;
            }
        }
        // --- stage W tile (32 x COUT) ---
        {
            constexpr int TOT4 = KC * COUT / 4;
#pragma unroll
            for (int i = t; i < TOT4; i += 256) {
                int k = (i * 4) / COUT;
                int c = (i * 4) % COUT;
                *(float4*)&Ws[k][c] = *(const float4*)&W[(size_t)(kc + k) * COUT + c];
            }
        }
        __syncthreads();

#pragma unroll
        for (int k = 0; k < KC; ++k) {
            float4 w = *(float4*)&Ws[k][tx * 4];
            float a[RPT];
            *(float4*)&a[0] = *(float4*)&As[k][ty * RPT];
            if (RPT == 8) *(float4*)&a[4] = *(float4*)&As[k][ty * RPT + 4];
#pragma unroll
            for (int i = 0; i < RPT; ++i) {
                acc[i][0] += a[i] * w.x;
                acc[i][1] += a[i] * w.y;
                acc[i][2] += a[i] * w.z;
                acc[i][3] += a[i] * w.w;
            }
        }
        __syncthreads();
    }

#pragma unroll
    for (int i = 0; i < RPT; ++i) {
        int grow = row0 + ty * RPT + i;
        if (grow < M) {
            float4 v = make_float4(acc[i][0], acc[i][1], acc[i][2], acc[i][3]);
            *(float4*)&C[(size_t)grow * COUT + tx * 4] = v;
        }
    }
}

// ---------------- scatter-add:  out[col[e]] += h[row[e]] * norm[e] ----------------
template <int C>
__global__ __launch_bounds__(256) void scatter_kernel(const float* __restrict__ h, const int* __restrict__ row,
                                                      const int* __restrict__ col, const float* __restrict__ norm,
                                                      float* __restrict__ out, int E) {
    constexpr int TPE = C / 4;  // threads per edge
    long long t = (long long)blockIdx.x * 256 + threadIdx.x;
    long long e = t / TPE;
    if (e >= E) return;
    int c4 = (int)(t % TPE) * 4;
    int r = row[e];
    int c = col[e];
    float nm = norm[e];
    float4 v = *(const float4*)&h[(size_t)r * C + c4];
    float* dst = &out[(size_t)c * C + c4];
    atomicAdd(dst + 0, v.x * nm);
    atomicAdd(dst + 1, v.y * nm);
    atomicAdd(dst + 2, v.z * nm);
    atomicAdd(dst + 3, v.w * nm);
}

extern "C" void kernel_launch(void* const* d_in, const int* in_sizes, int n_in,
                              void* d_out, int out_size, void* d_ws, size_t ws_size,
                              hipStream_t stream) {
    const float* x  = (const float*)d_in[0];
    const int*   ei = (const int*)d_in[1];     // edge_index, [2, E]
    const float* W1 = (const float*)d_in[2];
    const float* b1 = (const float*)d_in[3];
    const float* W2 = (const float*)d_in[4];
    const float* b2 = (const float*)d_in[5];
    const float* W3 = (const float*)d_in[6];
    const float* b3 = (const float*)d_in[7];

    const int N = in_sizes[0] / 128;           // 100000
    const int E = in_sizes[1] / 2;             // 1600000
    const int* row = ei;
    const int* col = ei + E;

    float* ws    = (float*)d_ws;
    float* deg   = ws;                         // N floats (becomes dinv in-place)
    float* norm  = ws + N;                     // E floats
    float* bufA  = ws + N + E;                 // N*128 floats  ((N+E)*4 = 6.8MB, 16B aligned)
    float* bufB  = bufA + (size_t)N * 128;     // N*128 floats
    float* out   = (float*)d_out;              // N*64 floats

    const long long NC128 = (long long)N * 128;
    const long long NC64  = (long long)N * 64;

    // degree + symmetric norm
    hipMemsetAsync(deg, 0, (size_t)N * sizeof(float), stream);
    deg_kernel<<<cdiv_ll(E, 256), 256, 0, stream>>>(col, deg, E);
    dinv_kernel<<<cdiv_ll(N, 256), 256, 0, stream>>>(deg, N);
    norm_kernel<<<cdiv_ll(E, 256), 256, 0, stream>>>(row, col, deg, norm, E);

    // ---- layer 1: h1 = x @ W1 ; agg1 = b1 + scatter(h1) ----
    init_bias_kernel<128><<<cdiv_ll(NC128, 256), 256, 0, stream>>>(bufB, b1, NC128);
    gemm_kernel<128, false><<<cdiv_ll(N, TILE_M), 256, 0, stream>>>(x, W1, bufA, N);
    scatter_kernel<128><<<cdiv_ll((long long)E * 32, 256), 256, 0, stream>>>(bufA, row, col, norm, bufB, E);

    // ---- layer 2: h2 = relu(agg1) @ W2 ; agg2 = b2 + scatter(h2) ----
    gemm_kernel<128, true><<<cdiv_ll(N, TILE_M), 256, 0, stream>>>(bufB, W2, bufA, N);
    init_bias_kernel<128><<<cdiv_ll(NC128, 256), 256, 0, stream>>>(bufB, b2, NC128);
    scatter_kernel<128><<<cdiv_ll((long long)E * 32, 256), 256, 0, stream>>>(bufA, row, col, norm, bufB, E);

    // ---- layer 3: h3 = relu(agg2) @ W3 ; out = b3 + scatter(h3) ----
    gemm_kernel<64, true><<<cdiv_ll(N, TILE_M), 256, 0, stream>>>(bufB, W3, bufA, N);
    init_bias_kernel<64><<<cdiv_ll(NC64, 256), 256, 0, stream>>>(out, b3, NC64);
    scatter_kernel<64><<<cdiv_ll((long long)E * 16, 256), 256, 0, stream>>>(bufA, row, col, norm, out, E);
}

// Round 2
// 894.899 us; speedup vs baseline: 7.7774x; 7.7774x over previous
//
#include <hip/hip_runtime.h>
#include <hip/hip_bf16.h>

// GCN 3-layer, atomic-free. Per layer: g = dinv[n]*(act(A[n])@W)  (dinv fused in GEMM
// epilogue); agg[c] = dinv[c]*sum_{e: col=c} g[row_e] + b  (CSR-by-destination gather,
// one wave per node). ReLU fused into next GEMM's A-load. CSR built per call:
// count -> block-scan -> fill. No atomics in the hot path.

#define K_DIM 128
#define KC 32
#define TILE_M 64
#define SCAN_CHUNK 1024   // elements per scan1 block (256 thr x 4)

static inline long long cdiv_ll(long long a, long long b) { return (a + b - 1) / b; }

// ---------------- CSR build ----------------
__global__ __launch_bounds__(256) void count_kernel(const int* __restrict__ col, int* __restrict__ cnt, int E) {
    int e = blockIdx.x * 256 + threadIdx.x;
    if (e < E) atomicAdd(&cnt[col[e]], 1);
}

__global__ __launch_bounds__(256) void dinv_kernel(const int* __restrict__ cnt, float* __restrict__ dinv, int N) {
    int n = blockIdx.x * 256 + threadIdx.x;
    if (n < N) {
        int d = cnt[n];
        dinv[n] = (d > 0) ? (1.0f / sqrtf((float)d)) : 0.0f;
    }
}

__global__ __launch_bounds__(256) void scan1_kernel(const int* __restrict__ cnt, int* __restrict__ off,
                                                    int* __restrict__ bsum, int N) {
    __shared__ int lds[256];
    const int t = threadIdx.x;
    const int base = blockIdx.x * SCAN_CHUNK;
    int v[4], s = 0;
#pragma unroll
    for (int j = 0; j < 4; ++j) {
        int i = base + t * 4 + j;
        v[j] = (i < N) ? cnt[i] : 0;
        s += v[j];
    }
    lds[t] = s;
    __syncthreads();
    for (int d = 1; d < 256; d <<= 1) {
        int x = (t >= d) ? lds[t - d] : 0;
        __syncthreads();
        lds[t] += x;
        __syncthreads();
    }
    int excl = lds[t] - s;
    if (t == 255) bsum[blockIdx.x] = lds[255];
    int run = excl;
#pragma unroll
    for (int j = 0; j < 4; ++j) {
        int i = base + t * 4 + j;
        if (i < N) off[i] = run;
        run += v[j];
    }
}

__global__ __launch_bounds__(256) void scan2_kernel(int* __restrict__ bsum, int G, int* __restrict__ off,
                                                    int N, int E) {
    __shared__ int lds[256];
    const int t = threadIdx.x;
    int s = (t < G) ? bsum[t] : 0;
    lds[t] = s;
    __syncthreads();
    for (int d = 1; d < 256; d <<= 1) {
        int x = (t >= d) ? lds[t - d] : 0;
        __syncthreads();
        lds[t] += x;
        __syncthreads();
    }
    if (t < G) bsum[t] = lds[t] - s;  // exclusive
    if (t == 0) off[N] = E;
}

__global__ __launch_bounds__(256) void scan3_kernel(int* __restrict__ off, const int* __restrict__ bsum, int N) {
    int add = bsum[blockIdx.x];
    const int base = blockIdx.x * SCAN_CHUNK;
#pragma unroll
    for (int j = 0; j < 4; ++j) {
        int i = base + threadIdx.x * 4 + j;
        if (i < N) off[i] += add;
    }
}

__global__ __launch_bounds__(256) void fill_kernel(const int* __restrict__ row, const int* __restrict__ col,
                                                   const int* __restrict__ off, int* __restrict__ cur,
                                                   int* __restrict__ csr_row, int E) {
    int e = blockIdx.x * 256 + threadIdx.x;
    if (e < E) {
        int c = col[e];
        int p = atomicAdd(&cur[c], 1);
        csr_row[off[c] + p] = row[e];
    }
}

// ---------------- fp32 tiled GEMM:  C[n] = dinv[n] * (act(A[n, :128]) @ W[128 x COUT]) ----------------
template <int COUT, bool RELU>
__global__ __launch_bounds__(256) void gemm_kernel(const float* __restrict__ A, const float* __restrict__ W,
                                                   const float* __restrict__ dinv, float* __restrict__ C, int M) {
    constexpr int TX = COUT / 4;
    constexpr int TY = 256 / TX;
    constexpr int RPT = TILE_M / TY;
    constexpr int AS_STRIDE = TILE_M + 4;

    __shared__ float As[KC][AS_STRIDE];
    __shared__ float Ws[KC][COUT];

    const int t = threadIdx.x;
    const int tx = t % TX;
    const int ty = t / TX;
    const int row0 = blockIdx.x * TILE_M;

    float acc[RPT][4];
#pragma unroll
    for (int i = 0; i < RPT; ++i)
#pragma unroll
        for (int j = 0; j < 4; ++j) acc[i][j] = 0.0f;

    for (int kc = 0; kc < K_DIM; kc += KC) {
        {
            int r = t / 8;
            int k4 = (t % 8) * 4;
#pragma unroll
            for (int pass = 0; pass < 2; ++pass) {
                int rr = r + pass * 32;
                int grow = row0 + rr;
                float4 v = make_float4(0.f, 0.f, 0.f, 0.f);
                if (grow < M) v = *(const float4*)&A[(size_t)grow * K_DIM + kc + k4];
                if (RELU) {
                    v.x = fmaxf(v.x, 0.f); v.y = fmaxf(v.y, 0.f);
                    v.z = fmaxf(v.z, 0.f); v.w = fmaxf(v.w, 0.f);
                }
                As[k4 + 0][rr] = v.x; As[k4 + 1][rr] = v.y;
                As[k4 + 2][rr] = v.z; As[k4 + 3][rr] = v.w;
            }
        }
        {
            constexpr int TOT4 = KC * COUT / 4;
#pragma unroll
            for (int i = t; i < TOT4; i += 256) {
                int k = (i * 4) / COUT;
                int c = (i * 4) % COUT;
                *(float4*)&Ws[k][c] = *(const float4*)&W[(size_t)(kc + k) * COUT + c];
            }
        }
        __syncthreads();

#pragma unroll
        for (int k = 0; k < KC; ++k) {
            float4 w = *(float4*)&Ws[k][tx * 4];
            float a[RPT];
            *(float4*)&a[0] = *(float4*)&As[k][ty * RPT];
            if (RPT == 8) *(float4*)&a[4] = *(float4*)&As[k][ty * RPT + 4];
#pragma unroll
            for (int i = 0; i < RPT; ++i) {
                acc[i][0] += a[i] * w.x;
                acc[i][1] += a[i] * w.y;
                acc[i][2] += a[i] * w.z;
                acc[i][3] += a[i] * w.w;
            }
        }
        __syncthreads();
    }

#pragma unroll
    for (int i = 0; i < RPT; ++i) {
        int grow = row0 + ty * RPT + i;
        if (grow < M) {
            float dv = dinv[grow];
            float4 v = make_float4(acc[i][0] * dv, acc[i][1] * dv, acc[i][2] * dv, acc[i][3] * dv);
            *(float4*)&C[(size_t)grow * COUT + tx * 4] = v;
        }
    }
}

// ---------------- CSR gather:  out[n] = dinv[n] * sum_{s in [off[n],off[n+1])} g[csr_row[s]] + b ----------------
// one wave per node; C=128 -> float2/lane, C=64 -> float/lane
template <int C>
__global__ __launch_bounds__(256) void gather_kernel(const float* __restrict__ g, const int* __restrict__ off,
                                                     const int* __restrict__ csr_row, const float* __restrict__ dinv,
                                                     const float* __restrict__ b, float* __restrict__ out, int N) {
    const int wave = (blockIdx.x * 256 + threadIdx.x) >> 6;
    const int lane = threadIdx.x & 63;
    if (wave >= N) return;
    const int s0 = off[wave];
    const int s1 = off[wave + 1];

    if (C == 128) {
        float2 acc = make_float2(0.f, 0.f);
        for (int s = s0; s < s1; ++s) {
            int r = csr_row[s];
            float2 v = *(const float2*)&g[(size_t)r * 128 + lane * 2];
            acc.x += v.x;
            acc.y += v.y;
        }
        float dv = dinv[wave];
        float2 o;
        o.x = acc.x * dv + b[lane * 2 + 0];
        o.y = acc.y * dv + b[lane * 2 + 1];
        *(float2*)&out[(size_t)wave * 128 + lane * 2] = o;
    } else {
        float acc = 0.f;
        for (int s = s0; s < s1; ++s) {
            int r = csr_row[s];
            acc += g[(size_t)r * 64 + lane];
        }
        out[(size_t)wave * 64 + lane] = acc * dinv[wave] + b[lane];
    }
}

extern "C" void kernel_launch(void* const* d_in, const int* in_sizes, int n_in,
                              void* d_out, int out_size, void* d_ws, size_t ws_size,
                              hipStream_t stream) {
    const float* x  = (const float*)d_in[0];
    const int*   ei = (const int*)d_in[1];
    const float* W1 = (const float*)d_in[2];
    const float* b1 = (const float*)d_in[3];
    const float* W2 = (const float*)d_in[4];
    const float* b2 = (const float*)d_in[5];
    const float* W3 = (const float*)d_in[6];
    const float* b3 = (const float*)d_in[7];

    const int N = in_sizes[0] / 128;   // 100000
    const int E = in_sizes[1] / 2;     // 1600000
    const int* row = ei;
    const int* col = ei + E;
    const int G = (int)cdiv_ll(N, SCAN_CHUNK);   // scan blocks (<=256 required)

    // workspace layout
    char* wsb = (char*)d_ws;
    int*   cnt     = (int*)wsb;                           wsb += (size_t)N * 4;        // counts, reused as cursor
    float* dinv    = (float*)wsb;                         wsb += (size_t)N * 4;
    int*   off     = (int*)wsb;                           wsb += (size_t)(N + 1) * 4;
    int*   bsum    = (int*)wsb;                           wsb += 256 * 4;
    int*   csr_row = (int*)wsb;                           wsb += (size_t)E * 4;
    float* bufA    = (float*)((((uintptr_t)wsb) + 15) & ~(uintptr_t)15);
    float* bufB    = bufA + (size_t)N * 128;
    float* out     = (float*)d_out;

    // ---- CSR build + dinv ----
    hipMemsetAsync(cnt, 0, (size_t)N * 4, stream);
    count_kernel<<<cdiv_ll(E, 256), 256, 0, stream>>>(col, cnt, E);
    dinv_kernel<<<cdiv_ll(N, 256), 256, 0, stream>>>(cnt, dinv, N);
    scan1_kernel<<<G, 256, 0, stream>>>(cnt, off, bsum, N);
    scan2_kernel<<<1, 256, 0, stream>>>(bsum, G, off, N, E);
    scan3_kernel<<<G, 256, 0, stream>>>(off, bsum, N);
    hipMemsetAsync(cnt, 0, (size_t)N * 4, stream);       // reuse as fill cursor
    fill_kernel<<<cdiv_ll(E, 256), 256, 0, stream>>>(row, col, off, cnt, csr_row, E);

    const long long gatherBlocks = cdiv_ll(N, 4);        // 4 waves/block, 1 wave/node

    // ---- layer 1 ----
    gemm_kernel<128, false><<<cdiv_ll(N, TILE_M), 256, 0, stream>>>(x, W1, dinv, bufA, N);
    gather_kernel<128><<<gatherBlocks, 256, 0, stream>>>(bufA, off, csr_row, dinv, b1, bufB, N);

    // ---- layer 2 ----
    gemm_kernel<128, true><<<cdiv_ll(N, TILE_M), 256, 0, stream>>>(bufB, W2, dinv, bufA, N);
    gather_kernel<128><<<gatherBlocks, 256, 0, stream>>>(bufA, off, csr_row, dinv, b2, bufB, N);

    // ---- layer 3 ----
    gemm_kernel<64, true><<<cdiv_ll(N, TILE_M), 256, 0, stream>>>(bufB, W3, dinv, bufA, N);
    gather_kernel<64><<<gatherBlocks, 256, 0, stream>>>(bufA, off, csr_row, dinv, b3, out, N);
}

// Round 3
// 561.863 us; speedup vs baseline: 12.3874x; 1.5927x over previous
//
#include <hip/hip_runtime.h>
#include <hip/hip_bf16.h>
#include <hip/hip_fp16.h>

// GCN 3-layer, atomic-free, fp16 storage / fp32 compute.
// Per layer: g = dinv[n]*(A[n]@W) via MFMA f16 (dinv in epilogue, fp32 acc);
//            agg[c] = relu(dinv[c]*sum_{e:col=c} g[row_e] + b) via CSR gather (1 wave/node).
// W pre-packed per call into MFMA B-fragment layout; staged once per block in LDS.
// Verified layouts (learn_hip m89/m120): A[m=lane&15][k=(lane>>4)*8+j],
// B[k=(lane>>4)*8+j][n=lane&15], C/D[row=(lane>>4)*4+reg][col=lane&15].

#define K_DIM 128
#define SCAN_CHUNK 1024

typedef _Float16 f16x8 __attribute__((ext_vector_type(8)));
typedef float f32x4 __attribute__((ext_vector_type(4)));
struct h2s { _Float16 x, y; };

static inline long long cdiv_ll(long long a, long long b) { return (a + b - 1) / b; }

// ---------------- CSR build ----------------
__global__ __launch_bounds__(256) void count_kernel(const int* __restrict__ col, int* __restrict__ cnt, int E) {
    int e = blockIdx.x * 256 + threadIdx.x;
    if (e < E) atomicAdd(&cnt[col[e]], 1);
}

__global__ __launch_bounds__(256) void dinv_kernel(const int* __restrict__ cnt, float* __restrict__ dinv, int N) {
    int n = blockIdx.x * 256 + threadIdx.x;
    if (n < N) {
        int d = cnt[n];
        dinv[n] = (d > 0) ? (1.0f / sqrtf((float)d)) : 0.0f;
    }
}

__global__ __launch_bounds__(256) void scan1_kernel(const int* __restrict__ cnt, int* __restrict__ off,
                                                    int* __restrict__ bsum, int N) {
    __shared__ int lds[256];
    const int t = threadIdx.x;
    const int base = blockIdx.x * SCAN_CHUNK;
    int v[4], s = 0;
#pragma unroll
    for (int j = 0; j < 4; ++j) {
        int i = base + t * 4 + j;
        v[j] = (i < N) ? cnt[i] : 0;
        s += v[j];
    }
    lds[t] = s;
    __syncthreads();
    for (int d = 1; d < 256; d <<= 1) {
        int x = (t >= d) ? lds[t - d] : 0;
        __syncthreads();
        lds[t] += x;
        __syncthreads();
    }
    int excl = lds[t] - s;
    if (t == 255) bsum[blockIdx.x] = lds[255];
    int run = excl;
#pragma unroll
    for (int j = 0; j < 4; ++j) {
        int i = base + t * 4 + j;
        if (i < N) off[i] = run;
        run += v[j];
    }
}

__global__ __launch_bounds__(256) void scan2_kernel(int* __restrict__ bsum, int G, int* __restrict__ off,
                                                    int N, int E) {
    __shared__ int lds[256];
    const int t = threadIdx.x;
    int s = (t < G) ? bsum[t] : 0;
    lds[t] = s;
    __syncthreads();
    for (int d = 1; d < 256; d <<= 1) {
        int x = (t >= d) ? lds[t - d] : 0;
        __syncthreads();
        lds[t] += x;
        __syncthreads();
    }
    if (t < G) bsum[t] = lds[t] - s;
    if (t == 0) off[N] = E;
}

__global__ __launch_bounds__(256) void scan3_kernel(int* __restrict__ off, const int* __restrict__ bsum, int N) {
    int add = bsum[blockIdx.x];
    const int base = blockIdx.x * SCAN_CHUNK;
#pragma unroll
    for (int j = 0; j < 4; ++j) {
        int i = base + threadIdx.x * 4 + j;
        if (i < N) off[i] += add;
    }
}

__global__ __launch_bounds__(256) void fill_kernel(const int* __restrict__ row, const int* __restrict__ col,
                                                   const int* __restrict__ off, int* __restrict__ cur,
                                                   int* __restrict__ csr_row, int E) {
    int e = blockIdx.x * 256 + threadIdx.x;
    if (e < E) {
        int c = col[e];
        int p = atomicAdd(&cur[c], 1);
        csr_row[off[c] + p] = row[e];
    }
}

// ---------------- W pack: fp32 [K][COUT] -> fp16 MFMA B-fragment order ----------------
template <int COUT>
__global__ __launch_bounds__(256) void pack_w_kernel(const float* __restrict__ W, _Float16* __restrict__ Wp) {
    constexpr int NT = COUT / 16;
    int t = blockIdx.x * 256 + threadIdx.x;
    if (t >= 4 * NT * 64) return;
    int lane = t & 63;
    int nt = (t >> 6) % NT;
    int kt = t / (64 * NT);
    int c = lane & 15, q = lane >> 4;
    f16x8 v;
#pragma unroll
    for (int j = 0; j < 8; ++j) {
        int k = kt * 32 + q * 8 + j;
        v[j] = (_Float16)W[k * COUT + nt * 16 + c];
    }
    *(f16x8*)&Wp[(size_t)t * 8] = v;
}

// ---------------- MFMA GEMM: g[n] = dinv[n] * (A[n,:128] @ W)  (A fp32 or fp16, out fp16) ----------------
template <int COUT, bool AF16>
__global__ __launch_bounds__(256) void gemm_mfma(const void* __restrict__ Av, const _Float16* __restrict__ Wp,
                                                 const float* __restrict__ dinv, _Float16* __restrict__ Cmat, int M) {
    constexpr int NT = COUT / 16;
    constexpr int NFRAG = 4 * NT * 64;           // f16x8 fragments
    __shared__ _Float16 Wlds[NFRAG * 8];         // 32KB (COUT=128) / 16KB (COUT=64)

    const int t = threadIdx.x;
    for (int i = t; i < NFRAG; i += 256)
        *(f16x8*)&Wlds[(size_t)i * 8] = *(const f16x8*)&Wp[(size_t)i * 8];
    __syncthreads();

    const int lane = t & 63;
    const int wave = t >> 6;
    const int c = lane & 15;
    const int q = lane >> 4;
    const int row_base = blockIdx.x * 128 + wave * 32;   // 2 row-tiles of 16 per wave

    f32x4 acc[2][NT];
#pragma unroll
    for (int rt = 0; rt < 2; ++rt)
#pragma unroll
        for (int nt = 0; nt < NT; ++nt) {
            acc[rt][nt][0] = 0.f; acc[rt][nt][1] = 0.f;
            acc[rt][nt][2] = 0.f; acc[rt][nt][3] = 0.f;
        }

#pragma unroll
    for (int kt = 0; kt < 4; ++kt) {
        f16x8 a[2];
#pragma unroll
        for (int rt = 0; rt < 2; ++rt) {
            int r = row_base + rt * 16 + c;
            r = (r < M) ? r : (M - 1);
            if (AF16) {
                a[rt] = *(const f16x8*)((const _Float16*)Av + (size_t)r * K_DIM + kt * 32 + q * 8);
            } else {
                const float* ap = (const float*)Av + (size_t)r * K_DIM + kt * 32 + q * 8;
                float4 v0 = *(const float4*)ap;
                float4 v1 = *(const float4*)(ap + 4);
                f16x8 av;
                av[0] = (_Float16)v0.x; av[1] = (_Float16)v0.y;
                av[2] = (_Float16)v0.z; av[3] = (_Float16)v0.w;
                av[4] = (_Float16)v1.x; av[5] = (_Float16)v1.y;
                av[6] = (_Float16)v1.z; av[7] = (_Float16)v1.w;
                a[rt] = av;
            }
        }
#pragma unroll
        for (int nt = 0; nt < NT; ++nt) {
            f16x8 b = *(const f16x8*)&Wlds[(size_t)((kt * NT + nt) * 64 + lane) * 8];
            acc[0][nt] = __builtin_amdgcn_mfma_f32_16x16x32_f16(a[0], b, acc[0][nt], 0, 0, 0);
            acc[1][nt] = __builtin_amdgcn_mfma_f32_16x16x32_f16(a[1], b, acc[1][nt], 0, 0, 0);
        }
    }

#pragma unroll
    for (int rt = 0; rt < 2; ++rt)
#pragma unroll
        for (int reg = 0; reg < 4; ++reg) {
            int row = row_base + rt * 16 + q * 4 + reg;
            if (row < M) {
                float dv = dinv[row];
#pragma unroll
                for (int nt = 0; nt < NT; ++nt)
                    Cmat[(size_t)row * COUT + nt * 16 + c] = (_Float16)(acc[rt][nt][reg] * dv);
            }
        }
}

// ---------------- CSR gather: out[n] = act(dinv[n]*sum g[csr_row[s]] + b), 1 wave/node ----------------
template <int C, bool RELU, typename OutT>
__global__ __launch_bounds__(256) void gather_kernel(const _Float16* __restrict__ g, const int* __restrict__ off,
                                                     const int* __restrict__ csr_row, const float* __restrict__ dinv,
                                                     const float* __restrict__ bias, OutT* __restrict__ out, int N) {
    const int wave = (blockIdx.x * 256 + threadIdx.x) >> 6;
    const int lane = threadIdx.x & 63;
    if (wave >= N) return;
    const int s0 = off[wave];
    const int s1 = off[wave + 1];
    const float dv = dinv[wave];

    if (C == 128) {
        float ax = 0.f, ay = 0.f;
        int s = s0;
        for (; s + 4 <= s1; s += 4) {
            int r0 = csr_row[s], r1 = csr_row[s + 1], r2 = csr_row[s + 2], r3 = csr_row[s + 3];
            h2s v0 = *(const h2s*)&g[(size_t)r0 * 128 + lane * 2];
            h2s v1 = *(const h2s*)&g[(size_t)r1 * 128 + lane * 2];
            h2s v2 = *(const h2s*)&g[(size_t)r2 * 128 + lane * 2];
            h2s v3 = *(const h2s*)&g[(size_t)r3 * 128 + lane * 2];
            ax += (float)v0.x + (float)v1.x + (float)v2.x + (float)v3.x;
            ay += (float)v0.y + (float)v1.y + (float)v2.y + (float)v3.y;
        }
        for (; s < s1; ++s) {
            h2s v = *(const h2s*)&g[(size_t)csr_row[s] * 128 + lane * 2];
            ax += (float)v.x;
            ay += (float)v.y;
        }
        float ox = ax * dv + bias[lane * 2 + 0];
        float oy = ay * dv + bias[lane * 2 + 1];
        if (RELU) { ox = fmaxf(ox, 0.f); oy = fmaxf(oy, 0.f); }
        if constexpr (sizeof(OutT) == 2) {
            h2s o; o.x = (_Float16)ox; o.y = (_Float16)oy;
            *(h2s*)((_Float16*)out + (size_t)wave * 128 + lane * 2) = o;
        } else {
            float2 o = make_float2(ox, oy);
            *(float2*)((float*)out + (size_t)wave * 128 + lane * 2) = o;
        }
    } else {
        float a0 = 0.f;
        int s = s0;
        for (; s + 4 <= s1; s += 4) {
            int r0 = csr_row[s], r1 = csr_row[s + 1], r2 = csr_row[s + 2], r3 = csr_row[s + 3];
            a0 += (float)g[(size_t)r0 * 64 + lane] + (float)g[(size_t)r1 * 64 + lane] +
                  (float)g[(size_t)r2 * 64 + lane] + (float)g[(size_t)r3 * 64 + lane];
        }
        for (; s < s1; ++s) a0 += (float)g[(size_t)csr_row[s] * 64 + lane];
        float o = a0 * dv + bias[lane];
        if (RELU) o = fmaxf(o, 0.f);
        ((OutT*)out)[(size_t)wave * 64 + lane] = (OutT)o;
    }
}

extern "C" void kernel_launch(void* const* d_in, const int* in_sizes, int n_in,
                              void* d_out, int out_size, void* d_ws, size_t ws_size,
                              hipStream_t stream) {
    const float* x  = (const float*)d_in[0];
    const int*   ei = (const int*)d_in[1];
    const float* W1 = (const float*)d_in[2];
    const float* b1 = (const float*)d_in[3];
    const float* W2 = (const float*)d_in[4];
    const float* b2 = (const float*)d_in[5];
    const float* W3 = (const float*)d_in[6];
    const float* b3 = (const float*)d_in[7];

    const int N = in_sizes[0] / 128;   // 100000
    const int E = in_sizes[1] / 2;     // 1600000
    const int* row = ei;
    const int* col = ei + E;
    const int G = (int)cdiv_ll(N, SCAN_CHUNK);

    // workspace layout
    char* wsb = (char*)d_ws;
    int*      cnt     = (int*)wsb;      wsb += (size_t)N * 4;
    float*    dinv    = (float*)wsb;    wsb += (size_t)N * 4;
    int*      off     = (int*)wsb;      wsb += (size_t)(N + 1) * 4;
    int*      bsum    = (int*)wsb;      wsb += 256 * 4;
    int*      csr_row = (int*)wsb;      wsb += (size_t)E * 4;
    wsb = (char*)((((uintptr_t)wsb) + 15) & ~(uintptr_t)15);
    _Float16* Wp1     = (_Float16*)wsb; wsb += 16384 * 2;   // 4*8*64*8 halves
    _Float16* Wp2     = (_Float16*)wsb; wsb += 16384 * 2;
    _Float16* Wp3     = (_Float16*)wsb; wsb += 8192 * 2;
    _Float16* bufA    = (_Float16*)wsb; wsb += (size_t)N * 128 * 2;
    _Float16* bufB    = (_Float16*)wsb;
    float*    out     = (float*)d_out;

    // ---- CSR build + dinv + W pack ----
    hipMemsetAsync(cnt, 0, (size_t)N * 4, stream);
    count_kernel<<<cdiv_ll(E, 256), 256, 0, stream>>>(col, cnt, E);
    dinv_kernel<<<cdiv_ll(N, 256), 256, 0, stream>>>(cnt, dinv, N);
    scan1_kernel<<<G, 256, 0, stream>>>(cnt, off, bsum, N);
    scan2_kernel<<<1, 256, 0, stream>>>(bsum, G, off, N, E);
    scan3_kernel<<<G, 256, 0, stream>>>(off, bsum, N);
    hipMemsetAsync(cnt, 0, (size_t)N * 4, stream);
    fill_kernel<<<cdiv_ll(E, 256), 256, 0, stream>>>(row, col, off, cnt, csr_row, E);
    pack_w_kernel<128><<<8, 256, 0, stream>>>(W1, Wp1);
    pack_w_kernel<128><<<8, 256, 0, stream>>>(W2, Wp2);
    pack_w_kernel<64><<<4, 256, 0, stream>>>(W3, Wp3);

    const long long gemmBlocks   = cdiv_ll(N, 128);
    const long long gatherBlocks = cdiv_ll(N, 4);

    // ---- layer 1 ----
    gemm_mfma<128, false><<<gemmBlocks, 256, 0, stream>>>(x, Wp1, dinv, bufA, N);
    gather_kernel<128, true, _Float16><<<gatherBlocks, 256, 0, stream>>>(bufA, off, csr_row, dinv, b1, bufB, N);

    // ---- layer 2 ----
    gemm_mfma<128, true><<<gemmBlocks, 256, 0, stream>>>(bufB, Wp2, dinv, bufA, N);
    gather_kernel<128, true, _Float16><<<gatherBlocks, 256, 0, stream>>>(bufA, off, csr_row, dinv, b2, bufB, N);

    // ---- layer 3 ----
    gemm_mfma<64, true><<<gemmBlocks, 256, 0, stream>>>(bufB, Wp3, dinv, bufA, N);
    gather_kernel<64, false, float><<<gatherBlocks, 256, 0, stream>>>(bufA, off, csr_row, dinv, b3, out, N);
}